// Round 1
// 190.887 us; speedup vs baseline: 1.0897x; 1.0897x over previous
//
#include <hip/hip_runtime.h>

typedef unsigned long long u64;
typedef unsigned int u32;

#define R_TOT 159882
#define POST 1000
#define IMG_SZ 800.0f
#define NMS_TH 0.7f
#define BBOX_CLIP 4.135166556742356f
#define LCAP 1024
#define TRI_FULL 7680   // 64 * 120 words: packed lower-triangle (tr=1..15) per level

__device__ __forceinline__ float fadd_(float a, float b){ return __fadd_rn(a,b); }
__device__ __forceinline__ float fsub_(float a, float b){ return __fsub_rn(a,b); }
__device__ __forceinline__ float fmul_(float a, float b){ return __fmul_rn(a,b); }

__device__ __forceinline__ int lvl_len(int l){ const int L[5]={120000,30000,7500,1875,507}; return L[l]; }
__device__ __forceinline__ int lvl_off(int l){ const int L[5]={0,120000,150000,157500,159375}; return L[l]; }
__device__ __forceinline__ int lvl_k(int l){ const int L[5]={1000,1000,1000,1000,507}; return L[l]; }

__device__ __forceinline__ u32 mono_(u32 u){ return (u & 0x80000000u) ? ~u : (u | 0x80000000u); }

__device__ __forceinline__ u64 readlane64(u64 v, int i){
  u32 lo = (u32)__builtin_amdgcn_readlane((int)(u32)v, i);
  u32 hi = (u32)__builtin_amdgcn_readlane((int)(u32)(v >> 32), i);
  return ((u64)hi << 32) | (u64)lo;
}

// ---------- 1. per-slice 12-bit histogram: LDS-private, full overwrite (no memset) ----------
// also zeroes the collect counters (was done by the removed k_pick)
__global__ __launch_bounds__(256) void k_hist(const float* __restrict__ obj, int* hist16,
                                              int* cntg, int* cnt2){
  int g = blockIdx.x, sl = blockIdx.y;
  int img = g/5, lvl = g%5;
  int n = lvl_len(lvl), s0 = lvl_off(lvl);
  __shared__ int lh[4096];
  int tid = threadIdx.x;
  for (int i = tid; i < 4096; i += 256) lh[i] = 0;
  if (sl == 0 && tid == 0){ cntg[g] = 0; cnt2[g] = 0; }
  __syncthreads();
  int lo = (int)((long long)n * sl / 16), hiS = (int)((long long)n * (sl+1) / 16);
  const float* p = obj + img*R_TOT + s0;
  #pragma unroll 4
  for (int e = lo + tid; e < hiS; e += 256){
    u32 mu = mono_(__float_as_uint(p[e]));
    atomicAdd(&lh[(~mu) >> 20], 1);
  }
  __syncthreads();
  int* dst = hist16 + (g*16 + sl)*4096;
  for (int i = tid; i < 4096; i += 256) dst[i] = lh[i];
}

// ---------- 2. collect with inlined pick: each block re-derives b*/rem from L2-hot hist16,
//             block-local LDS compaction, ONE global atomic per counter per block ----------
__global__ __launch_bounds__(256) void k_collect(const float* __restrict__ obj,
                                                 const int* __restrict__ hist16,
                                                 int* bstarG, int* remG,
                                                 int* cntg, int* cnt2,
                                                 u64* mainG, u64* LbufG){
  int g = blockIdx.x, sl = blockIdx.y;
  int img = g/5, lvl = g%5;
  int n = lvl_len(lvl), s0 = lvl_off(lvl), k = lvl_k(lvl);
  int tid = threadIdx.x, lane = tid & 63, wid = tid >> 6;
  __shared__ int wsum[4];
  __shared__ int sh_bs, sh_rem;
  __shared__ int lc, lc2, gbase, gbase2;
  __shared__ u64 lmain[1024];
  __shared__ u64 lbuf2[1024];

  // --- pick phase: 16 contiguous bins per thread, summed over 16 slices ---
  int h[16];
  #pragma unroll
  for (int j = 0; j < 16; j++) h[j] = 0;
  const int* hb = hist16 + g*16*4096 + 16*tid;
  for (int s2 = 0; s2 < 16; s2++){
    const int4* hs = (const int4*)(hb + s2*4096);
    int4 a = hs[0], b = hs[1], c = hs[2], d = hs[3];
    h[0]+=a.x;  h[1]+=a.y;  h[2]+=a.z;  h[3]+=a.w;
    h[4]+=b.x;  h[5]+=b.y;  h[6]+=b.z;  h[7]+=b.w;
    h[8]+=c.x;  h[9]+=c.y;  h[10]+=c.z; h[11]+=c.w;
    h[12]+=d.x; h[13]+=d.y; h[14]+=d.z; h[15]+=d.w;
  }
  int part = 0;
  #pragma unroll
  for (int j = 0; j < 16; j++) part += h[j];
  int x = part;
  for (int d = 1; d < 64; d <<= 1){ int y = __shfl_up(x, d); if (lane >= d) x += y; }
  if (lane == 63) wsum[wid] = x;
  if (tid == 0){ lc = 0; lc2 = 0; }
  __syncthreads();
  int add = 0;
  for (int w = 0; w < wid; w++) add += wsum[w];
  int incl = x + add, excl = incl - part;
  if (excl < k && k <= incl){
    int cum = excl;
    #pragma unroll
    for (int q = 0; q < 16; q++){
      if (cum + h[q] >= k){ sh_bs = 16*tid + q; sh_rem = k - cum; break; }
      cum += h[q];
    }
  }
  __syncthreads();
  int bs = sh_bs;
  if (sl == 0 && tid == 0){ bstarG[g] = bs; remG[g] = sh_rem; }

  // --- collect phase: block-local LDS lists ---
  int lo = (int)((long long)n * sl / 16), hiS = (int)((long long)n * (sl+1) / 16);
  const float* p = obj + img*R_TOT + s0;
  #pragma unroll 4
  for (int e = lo + tid; e < hiS; e += 256){
    u32 mu = mono_(__float_as_uint(p[e]));
    u64 key56 = (((u64)(~mu)) << 24) | (u32)(s0 + e);
    int bin = (int)(key56 >> 44);
    if (bin < bs){ int pos = atomicAdd(&lc, 1); lmain[pos] = key56; }          // pos < 1024 guaranteed (global bound k-rem <= 999)
    else if (bin == bs){ int pos = atomicAdd(&lc2, 1); if (pos < 1024) lbuf2[pos] = key56; }
  }
  __syncthreads();
  if (tid == 0){ gbase = atomicAdd(&cntg[g], lc); gbase2 = atomicAdd(&cnt2[g], lc2); }
  __syncthreads();
  int b1 = gbase, c1 = lc;
  for (int i = tid; i < c1; i += 256) mainG[g*1024 + b1 + i] = lmain[i];
  int b2 = gbase2, c2l = lc2 < 1024 ? lc2 : 1024;   // if a block clips here, total c2 > LCAP -> fallback ignores LbufG
  for (int i = tid; i < c2l; i += 256){
    int gp = b2 + i;
    if (gp < LCAP) LbufG[g*LCAP + gp] = lbuf2[i];
  }
}

// ---------- 3. tie-resolve + sort + decode + prep (okey written in compacted order) ----------
__global__ __launch_bounds__(1024) void k_seldecode(const float* __restrict__ obj,
                                                    const float4* __restrict__ deltas,
                                                    const float4* __restrict__ anchors,
                                                    const u64* __restrict__ mainG,
                                                    const u64* __restrict__ LbufG,
                                                    const int* __restrict__ cntg,
                                                    const int* __restrict__ cnt2,
                                                    const int* __restrict__ remG,
                                                    const int* __restrict__ bstarG,
                                                    float4* boxL, float* scoreL,
                                                    float4* nbox, u64* okeyN, int* ncnt){
  int g = blockIdx.x, img = g/5, lvl = g%5;
  int s0 = lvl_off(lvl), n = lvl_len(lvl), k = lvl_k(lvl);
  const float* p = obj + img*R_TOT + s0;
  __shared__ u64 Lbuf[LCAP];
  __shared__ u64 mainL[1024];
  __shared__ float4 lbox[1024];
  __shared__ u64 lokey[1024];
  __shared__ unsigned char lval[1024];
  __shared__ int h16[16];
  __shared__ int sh_sc, sh_rem;
  __shared__ u64 sh_thr;
  int tid = threadIdx.x, lane = tid & 63;
  int nb = cntg[g];
  int c2 = cnt2[g];
  int rem = remG[g];
  int bs = bstarG[g];
  mainL[tid] = (tid < nb) ? mainG[g*1024 + tid] : ~0ull;
  if (tid == 0){ sh_sc = 0; sh_rem = rem; }
  int c2c = c2 < LCAP ? c2 : LCAP;
  for (int e = tid; e < c2c; e += 1024) Lbuf[e] = LbufG[g*LCAP + e];
  __syncthreads();
  if (c2 <= LCAP){
    for (int e = tid; e < c2; e += 1024){
      u64 kk = Lbuf[e];
      int rk = 0;
      for (int q = 0; q < c2; q++) rk += (Lbuf[q] < kk) ? 1 : 0;
      if (rk < rem){ int p2 = atomicAdd(&sh_sc, 1); mainL[nb + p2] = kk; }
    }
  } else {
    // fallback: 4-bit radix refine over global (never hit on bench data)
    if (tid == 0) sh_thr = ((u64)bs) << 44;
    __syncthreads();
    for (int shift = 40; shift >= 0; shift -= 4){
      if (tid < 16) h16[tid] = 0;
      __syncthreads();
      u64 pref = sh_thr;
      u64 himask = ~((1ull << (shift+4)) - 1ull);
      for (int e = tid; e < n; e += 1024){
        u32 mu = mono_(__float_as_uint(p[e]));
        u64 kk = (((u64)(~mu)) << 24) | (u32)(s0 + e);
        if ((kk & himask) == (pref & himask)) atomicAdd(&h16[(int)((kk >> shift) & 15)], 1);
      }
      __syncthreads();
      if (tid == 0){
        int r2 = sh_rem, cum = 0;
        for (int d = 0; d < 16; d++){
          int hb = h16[d];
          if (cum + hb >= r2){ sh_thr = pref | ((u64)d << shift); sh_rem = r2 - cum; break; }
          cum += hb;
        }
      }
      __syncthreads();
    }
    u64 thr = sh_thr;
    for (int e = tid; e < n; e += 1024){
      u32 mu = mono_(__float_as_uint(p[e]));
      u64 kk = (((u64)(~mu)) << 24) | (u32)(s0 + e);
      if ((int)(kk >> 44) == bs && kk <= thr){ int p2 = atomicAdd(&sh_sc, 1); mainL[nb + p2] = kk; }
    }
  }
  __syncthreads();
  // --- bitonic sort 1024 ---
  for (int k2 = 2; k2 <= 1024; k2 <<= 1){
    for (int j = k2 >> 1; j > 0; j >>= 1){
      __syncthreads();
      int i = tid, ixj = i ^ j;
      if (ixj > i){
        u64 a = mainL[i], b = mainL[ixj];
        bool up = (i & k2) == 0;
        if ((a > b) == up){ mainL[i] = b; mainL[ixj] = a; }
      }
    }
  }
  __syncthreads();
  // --- decode + clip + valid + sigmoid + okey ---
  int r = tid, t = g*1024 + r;
  if (r < k){
    int idx = (int)(mainL[r] & 0xFFFFFFu);
    float4 a = anchors[idx];
    float4 d = deltas[img*R_TOT + idx];
    float o = obj[img*R_TOT + idx];
    float wa = fsub_(a.z, a.x), ha = fsub_(a.w, a.y);
    float cxa = fadd_(a.x, fmul_(0.5f, wa)), cya = fadd_(a.y, fmul_(0.5f, ha));
    float dw = fminf(d.z, BBOX_CLIP), dh = fminf(d.w, BBOX_CLIP);
    float cx = fadd_(fmul_(d.x, wa), cxa), cy = fadd_(fmul_(d.y, ha), cya);
    float w  = fmul_(expf(dw), wa),        h  = fmul_(expf(dh), ha);
    float x1 = fsub_(cx, fmul_(0.5f, w)), y1 = fsub_(cy, fmul_(0.5f, h));
    float x2 = fadd_(cx, fmul_(0.5f, w)), y2 = fadd_(cy, fmul_(0.5f, h));
    x1 = fminf(fmaxf(x1, 0.0f), IMG_SZ); y1 = fminf(fmaxf(y1, 0.0f), IMG_SZ);
    x2 = fminf(fmaxf(x2, 0.0f), IMG_SZ); y2 = fminf(fmaxf(y2, 0.0f), IMG_SZ);
    bool valid = (fsub_(x2, x1) >= 1e-3f) && (fsub_(y2, y1) >= 1e-3f);
    float e = expf(-o);
    float sig = __fdiv_rn(1.0f, fadd_(1.0f, e));
    float s = valid ? sig : -1.0f;
    u32 sb = __float_as_uint(s);
    u32 ms = (sb & 0x80000000u) ? ~sb : (sb | 0x80000000u);
    float4 b4 = make_float4(x1, y1, x2, y2);
    boxL[t] = b4;
    scoreL[t] = sig;
    lokey[r] = (((u64)(~ms)) << 32) | (u32)(lvl*1000 + r);
    lbox[r] = b4;
    lval[r] = valid ? 1 : 0;
  } else {
    lval[r] = 0;
  }
  __syncthreads();
  // --- valid-compaction (wave 0): nbox (+801*lvl offset) and okey in compacted order ---
  if (tid < 64){
    int cnt = 0;
    float off = (float)lvl * 801.0f;
    for (int base = 0; base < k; base += 64){
      int r2 = base + lane;
      bool v = (r2 < k) && lval[r2];
      float4 b = lbox[r2 < k ? r2 : 0];
      u64 mask = __ballot(v);
      int before = __popcll(mask & ((1ull << lane) - 1ull));
      if (v){
        int pos = cnt + before;
        nbox[g*1024 + pos] = make_float4(fadd_(b.x,off), fadd_(b.y,off), fadd_(b.z,off), fadd_(b.w,off));
        okeyN[g*1024 + pos] = lokey[r2];
      }
      cnt += __popcll(mask);
    }
    if (lane == 0) ncnt[g] = cnt;
  }
}

// ---------- 4. IoU bitmask: packed column-major triangle + forward diagonal words ----------
__global__ __launch_bounds__(64) void k_mask(const float4* __restrict__ nbox,
                                             const int* __restrict__ ncnt,
                                             u64* LTG, u64* diagF){
  int g = blockIdx.x, tr = blockIdx.y, tw = blockIdx.z;
  if (tw > tr) return;
  int m = ncnt[g];
  if (tr*64 >= m) return;
  __shared__ float4 shb[64];
  int lane = threadIdx.x;
  if (tw*64 + lane < m) shb[lane] = nbox[g*1024 + tw*64 + lane];
  __syncthreads();
  int j = tr*64 + lane;
  if (j >= m) return;
  float4 a = nbox[g*1024 + j];
  float areaA = fmul_(fsub_(a.z,a.x), fsub_(a.w,a.y));
  int imax = m - tw*64; if (imax > 64) imax = 64;
  if (tw == tr){
    // diagonal: only forward word (whom lane suppresses, ii > lane)
    u64 bitsF = 0;
    for (int ii = lane+1; ii < imax; ii++){
      float4 b = shb[ii];
      float ltx = fmaxf(a.x, b.x), lty = fmaxf(a.y, b.y);
      float rbx = fminf(a.z, b.z), rby = fminf(a.w, b.w);
      float wx = fmaxf(fsub_(rbx, ltx), 0.0f), wy = fmaxf(fsub_(rby, lty), 0.0f);
      float inter = fmul_(wx, wy);
      float areaB = fmul_(fsub_(b.z,b.x), fsub_(b.w,b.y));
      float den = fadd_(fsub_(fadd_(areaA, areaB), inter), 1e-9f);
      if (__fdiv_rn(inter, den) > NMS_TH) bitsF |= (1ull << ii);
    }
    diagF[g*1024 + j] = bitsF;
  } else {
    u64 bits = 0;
    for (int ii = 0; ii < imax; ii++){
      float4 b = shb[ii];
      float ltx = fmaxf(a.x, b.x), lty = fmaxf(a.y, b.y);
      float rbx = fminf(a.z, b.z), rby = fminf(a.w, b.w);
      float wx = fmaxf(fsub_(rbx, ltx), 0.0f), wy = fmaxf(fsub_(rby, lty), 0.0f);
      float inter = fmul_(wx, wy);
      float areaB = fmul_(fsub_(b.z,b.x), fsub_(b.w,b.y));
      float den = fadd_(fsub_(fadd_(areaA, areaB), inter), 1e-9f);
      if (__fdiv_rn(inter, den) > NMS_TH) bits |= (1ull << ii);
    }
    // packed column-major: word tw of row (tr*64+lane) at [tri(tr) + tw*64 + lane]
    LTG[(size_t)g*TRI_FULL + ((tr*(tr-1))/2 + tw)*64 + lane] = bits;
  }
}

__device__ __forceinline__ int lbound(const u64* a, int n, u64 key){
  int lo = 0, hi = n;
  while (lo < hi){ int mid = (lo + hi) >> 1; if (a[mid] < key) lo = mid + 1; else hi = mid; }
  return lo;
}

// ---------- 5. fused greedy scan + merge: waves 0-4 scan the 5 levels (L2-hot triangle,
//             kept runs compacted straight into LDS); waves 5-15 zero the output;
//             then rank by binary search and scatter ----------
__global__ __launch_bounds__(1024) void k_scanmerge(const u64* __restrict__ LTG,
                                                    const u64* __restrict__ diagF,
                                                    const int* __restrict__ ncnt,
                                                    const u64* __restrict__ okeyN,
                                                    const float4* __restrict__ boxL,
                                                    const float* __restrict__ scoreL,
                                                    float* out){
  int img = blockIdx.x, tid = threadIdx.x, lane = tid & 63, wid = tid >> 6;
  __shared__ u64 runs[5*1024];
  __shared__ u64 Kw[5][16];
  __shared__ int cl[5];
  if (wid < 5){
    int l = wid, g = img*5 + l;
    int m = ncnt[g];
    int nch = (m + 63) >> 6;
    const u64* LT = LTG + (size_t)g*TRI_FULL;
    int cnt = 0;
    for (int c = 0; c < nch; c++){
      int row = c*64 + lane;
      bool inr = row < m;
      u64 supp = 0;
      int tb = (c*(c-1)) >> 1;
      for (int q = 0; q < c; q++) supp |= LT[(tb+q)*64 + lane] & Kw[l][q];
      u64 fwd = inr ? diagF[g*1024 + row] : 0;
      u64 live = __ballot(inr && (supp == 0));
      u64 fz = __ballot(fwd != 0);
      u64 kept = 0;
      while (live){
        if (!(live & fz)){ kept |= live; break; }   // no remaining live lane suppresses anyone
        int i = __builtin_ctzll(live);
        kept |= (1ull << i);
        live &= ~(1ull << i);
        live &= ~readlane64(fwd, i);
      }
      Kw[l][c] = kept;                // uniform value; in-wave DS ordering suffices
      bool kp = (kept >> lane) & 1ull;
      int before = __popcll(kept & ((1ull << lane) - 1ull));
      if (kp) runs[l*1024 + cnt + before] = okeyN[g*1024 + c*64 + lane];
      cnt += __popcll(kept);
    }
    if (lane == 0) cl[l] = cnt;
  } else {
    // 704 threads zero the output while the scans run
    for (int t = tid - 320; t < POST; t += 704){
      out[img*POST*4 + t*4 + 0] = 0.0f;
      out[img*POST*4 + t*4 + 1] = 0.0f;
      out[img*POST*4 + t*4 + 2] = 0.0f;
      out[img*POST*4 + t*4 + 3] = 0.0f;
      out[2*POST*4 + img*POST + t] = -1.0f;
    }
  }
  __syncthreads();
  for (int idx = tid; idx < 5*1024; idx += 1024){
    int l = idx >> 10, i = idx & 1023;
    if (i < cl[l]){
      u64 key = runs[l*1024 + i];
      int rank = i;
      #pragma unroll
      for (int l2 = 0; l2 < 5; l2++)
        if (l2 != l) rank += lbound(runs + l2*1024, cl[l2], key);
      if (rank < POST){
        int pos = (int)(key & 0xFFFFFFFFull);
        int lvl = pos / 1000, r = pos - lvl*1000;
        int gg = img*5 + lvl;
        float4 bo = boxL[gg*1024 + r];
        float sc = scoreL[gg*1024 + r];
        out[img*POST*4 + rank*4 + 0] = bo.x;
        out[img*POST*4 + rank*4 + 1] = bo.y;
        out[img*POST*4 + rank*4 + 2] = bo.z;
        out[img*POST*4 + rank*4 + 3] = bo.w;
        out[2*POST*4 + img*POST + rank] = sc;
      }
    }
  }
}

extern "C" void kernel_launch(void* const* d_in, const int* in_sizes, int n_in,
                              void* d_out, int out_size, void* d_ws, size_t ws_size,
                              hipStream_t stream){
  (void)in_sizes; (void)n_in; (void)out_size; (void)ws_size;
  const float*  obj     = (const float*)d_in[0];
  const float4* deltas  = (const float4*)d_in[1];
  const float4* anchors = (const float4*)d_in[2];
  float* out = (float*)d_out;
  char* ws = (char*)d_ws;
  int* hist16  = (int*)(ws + 0);           // 10*16*4096 int -> 2621440
  int* bstarG  = (int*)(ws + 2621440);     //                -> 2621696
  int* remG    = (int*)(ws + 2621696);     //                -> 2621952
  int* cntg    = (int*)(ws + 2621952);     //                -> 2622208
  int* cnt2    = (int*)(ws + 2622208);     //                -> 2622464
  u64* mainG   = (u64*)(ws + 2622464);     // 10*1024 u64    -> 2704384
  u64* LbufG   = (u64*)(ws + 2704384);     // 10*1024 u64    -> 2786304
  float4* boxL = (float4*)(ws + 2786304);  // 10*1024 f4     -> 2950144
  float* scoreL= (float*)(ws + 2950144);   // 10*1024 f32    -> 2991104
  u64* okeyN   = (u64*)(ws + 2991104);     // 10*1024 u64    -> 3073024
  float4* nbox = (float4*)(ws + 3073024);  // 10*1024 f4     -> 3236864
  u64* LTG     = (u64*)(ws + 3236864);     // 10*7680 u64    -> 3851264
  u64* diagF   = (u64*)(ws + 3851264);     // 10*1024 u64    -> 3933184
  int* ncnt    = (int*)(ws + 3934464);     // 10 int

  {
    dim3 gh(10, 16);
    k_hist<<<gh, 256, 0, stream>>>(obj, hist16, cntg, cnt2);
  }
  {
    dim3 gc(10, 16);
    k_collect<<<gc, 256, 0, stream>>>(obj, hist16, bstarG, remG, cntg, cnt2, mainG, LbufG);
  }
  k_seldecode<<<10, 1024, 0, stream>>>(obj, deltas, anchors, mainG, LbufG, cntg, cnt2,
                                       remG, bstarG, boxL, scoreL, nbox, okeyN, ncnt);
  {
    dim3 gm(10, 16, 16);
    k_mask<<<gm, 64, 0, stream>>>(nbox, ncnt, LTG, diagF);
  }
  k_scanmerge<<<2, 1024, 0, stream>>>(LTG, diagF, ncnt, okeyN, boxL, scoreL, out);
}

// Round 2
// 175.224 us; speedup vs baseline: 1.1871x; 1.0894x over previous
//
#include <hip/hip_runtime.h>

typedef unsigned long long u64;
typedef unsigned int u32;

#define R_TOT 159882
#define POST 1000
#define IMG_SZ 800.0f
#define NMS_TH 0.7f
#define BBOX_CLIP 4.135166556742356f
#define LCAP 1024
#define TRI_FULL 7680   // 64 * 120 words: packed lower-triangle (tr=1..15) per level

__device__ __forceinline__ float fadd_(float a, float b){ return __fadd_rn(a,b); }
__device__ __forceinline__ float fsub_(float a, float b){ return __fsub_rn(a,b); }
__device__ __forceinline__ float fmul_(float a, float b){ return __fmul_rn(a,b); }

__device__ __forceinline__ int lvl_len(int l){ const int L[5]={120000,30000,7500,1875,507}; return L[l]; }
__device__ __forceinline__ int lvl_off(int l){ const int L[5]={0,120000,150000,157500,159375}; return L[l]; }
__device__ __forceinline__ int lvl_k(int l){ const int L[5]={1000,1000,1000,1000,507}; return L[l]; }

__device__ __forceinline__ u32 mono_(u32 u){ return (u & 0x80000000u) ? ~u : (u | 0x80000000u); }

__device__ __forceinline__ u64 readlane64(u64 v, int i){
  u32 lo = (u32)__builtin_amdgcn_readlane((int)(u32)v, i);
  u32 hi = (u32)__builtin_amdgcn_readlane((int)(u32)(v >> 32), i);
  return ((u64)hi << 32) | (u64)lo;
}

// ---------- 1. per-slice 12-bit histogram: LDS-private, full overwrite (no memset) ----------
// also zeroes the collect counters
__global__ __launch_bounds__(256) void k_hist(const float* __restrict__ obj, int* hist16,
                                              int* cntg, int* cnt2){
  int g = blockIdx.x, sl = blockIdx.y;
  int img = g/5, lvl = g%5;
  int n = lvl_len(lvl), s0 = lvl_off(lvl);
  __shared__ int lh[4096];
  int tid = threadIdx.x;
  for (int i = tid; i < 4096; i += 256) lh[i] = 0;
  if (sl == 0 && tid == 0){ cntg[g] = 0; cnt2[g] = 0; }
  __syncthreads();
  int lo = (int)((long long)n * sl / 16), hiS = (int)((long long)n * (sl+1) / 16);
  const float* p = obj + img*R_TOT + s0;
  #pragma unroll 4
  for (int e = lo + tid; e < hiS; e += 256){
    u32 mu = mono_(__float_as_uint(p[e]));
    atomicAdd(&lh[(~mu) >> 20], 1);
  }
  __syncthreads();
  int* dst = hist16 + (g*16 + sl)*4096;
  for (int i = tid; i < 4096; i += 256) dst[i] = lh[i];
}

// ---------- 2. collect with inlined pick: each block re-derives b*/rem from L2-hot hist16,
//             block-local LDS compaction, ONE global atomic per counter per block ----------
__global__ __launch_bounds__(256) void k_collect(const float* __restrict__ obj,
                                                 const int* __restrict__ hist16,
                                                 int* bstarG, int* remG,
                                                 int* cntg, int* cnt2,
                                                 u64* mainG, u64* LbufG){
  int g = blockIdx.x, sl = blockIdx.y;
  int img = g/5, lvl = g%5;
  int n = lvl_len(lvl), s0 = lvl_off(lvl), k = lvl_k(lvl);
  int tid = threadIdx.x, lane = tid & 63, wid = tid >> 6;
  __shared__ int wsum[4];
  __shared__ int sh_bs, sh_rem;
  __shared__ int lc, lc2, gbase, gbase2;
  __shared__ u64 lmain[1024];
  __shared__ u64 lbuf2[1024];

  // --- pick phase: 16 contiguous bins per thread, summed over 16 slices ---
  int h[16];
  #pragma unroll
  for (int j = 0; j < 16; j++) h[j] = 0;
  const int* hb = hist16 + g*16*4096 + 16*tid;
  for (int s2 = 0; s2 < 16; s2++){
    const int4* hs = (const int4*)(hb + s2*4096);
    int4 a = hs[0], b = hs[1], c = hs[2], d = hs[3];
    h[0]+=a.x;  h[1]+=a.y;  h[2]+=a.z;  h[3]+=a.w;
    h[4]+=b.x;  h[5]+=b.y;  h[6]+=b.z;  h[7]+=b.w;
    h[8]+=c.x;  h[9]+=c.y;  h[10]+=c.z; h[11]+=c.w;
    h[12]+=d.x; h[13]+=d.y; h[14]+=d.z; h[15]+=d.w;
  }
  int part = 0;
  #pragma unroll
  for (int j = 0; j < 16; j++) part += h[j];
  int x = part;
  for (int d = 1; d < 64; d <<= 1){ int y = __shfl_up(x, d); if (lane >= d) x += y; }
  if (lane == 63) wsum[wid] = x;
  if (tid == 0){ lc = 0; lc2 = 0; }
  __syncthreads();
  int add = 0;
  for (int w = 0; w < wid; w++) add += wsum[w];
  int incl = x + add, excl = incl - part;
  if (excl < k && k <= incl){
    int cum = excl;
    #pragma unroll
    for (int q = 0; q < 16; q++){
      if (cum + h[q] >= k){ sh_bs = 16*tid + q; sh_rem = k - cum; break; }
      cum += h[q];
    }
  }
  __syncthreads();
  int bs = sh_bs;
  if (sl == 0 && tid == 0){ bstarG[g] = bs; remG[g] = sh_rem; }

  // --- collect phase: block-local LDS lists ---
  int lo = (int)((long long)n * sl / 16), hiS = (int)((long long)n * (sl+1) / 16);
  const float* p = obj + img*R_TOT + s0;
  #pragma unroll 4
  for (int e = lo + tid; e < hiS; e += 256){
    u32 mu = mono_(__float_as_uint(p[e]));
    u64 key56 = (((u64)(~mu)) << 24) | (u32)(s0 + e);
    int bin = (int)(key56 >> 44);
    if (bin < bs){ int pos = atomicAdd(&lc, 1); lmain[pos] = key56; }          // pos < 1024 guaranteed (global bound k-rem <= 999)
    else if (bin == bs){ int pos = atomicAdd(&lc2, 1); if (pos < 1024) lbuf2[pos] = key56; }
  }
  __syncthreads();
  if (tid == 0){ gbase = atomicAdd(&cntg[g], lc); gbase2 = atomicAdd(&cnt2[g], lc2); }
  __syncthreads();
  int b1 = gbase, c1 = lc;
  for (int i = tid; i < c1; i += 256) mainG[g*1024 + b1 + i] = lmain[i];
  int b2 = gbase2, c2l = lc2 < 1024 ? lc2 : 1024;   // if a block clips here, total c2 > LCAP -> fallback ignores LbufG
  for (int i = tid; i < c2l; i += 256){
    int gp = b2 + i;
    if (gp < LCAP) LbufG[g*LCAP + gp] = lbuf2[i];
  }
}

// ---------- 3. tie-resolve + sort + decode + prep (okey written in compacted order) ----------
__global__ __launch_bounds__(1024) void k_seldecode(const float* __restrict__ obj,
                                                    const float4* __restrict__ deltas,
                                                    const float4* __restrict__ anchors,
                                                    const u64* __restrict__ mainG,
                                                    const u64* __restrict__ LbufG,
                                                    const int* __restrict__ cntg,
                                                    const int* __restrict__ cnt2,
                                                    const int* __restrict__ remG,
                                                    const int* __restrict__ bstarG,
                                                    float4* boxL, float* scoreL,
                                                    float4* nbox, u64* okeyN, int* ncnt){
  int g = blockIdx.x, img = g/5, lvl = g%5;
  int s0 = lvl_off(lvl), n = lvl_len(lvl), k = lvl_k(lvl);
  const float* p = obj + img*R_TOT + s0;
  __shared__ u64 Lbuf[LCAP];
  __shared__ u64 mainL[1024];
  __shared__ float4 lbox[1024];
  __shared__ u64 lokey[1024];
  __shared__ unsigned char lval[1024];
  __shared__ int h16[16];
  __shared__ int sh_sc, sh_rem;
  __shared__ u64 sh_thr;
  int tid = threadIdx.x, lane = tid & 63;
  int nb = cntg[g];
  int c2 = cnt2[g];
  int rem = remG[g];
  int bs = bstarG[g];
  mainL[tid] = (tid < nb) ? mainG[g*1024 + tid] : ~0ull;
  if (tid == 0){ sh_sc = 0; sh_rem = rem; }
  int c2c = c2 < LCAP ? c2 : LCAP;
  for (int e = tid; e < c2c; e += 1024) Lbuf[e] = LbufG[g*LCAP + e];
  __syncthreads();
  if (c2 <= LCAP){
    for (int e = tid; e < c2; e += 1024){
      u64 kk = Lbuf[e];
      int rk = 0;
      for (int q = 0; q < c2; q++) rk += (Lbuf[q] < kk) ? 1 : 0;
      if (rk < rem){ int p2 = atomicAdd(&sh_sc, 1); mainL[nb + p2] = kk; }
    }
  } else {
    // fallback: 4-bit radix refine over global (never hit on bench data)
    if (tid == 0) sh_thr = ((u64)bs) << 44;
    __syncthreads();
    for (int shift = 40; shift >= 0; shift -= 4){
      if (tid < 16) h16[tid] = 0;
      __syncthreads();
      u64 pref = sh_thr;
      u64 himask = ~((1ull << (shift+4)) - 1ull);
      for (int e = tid; e < n; e += 1024){
        u32 mu = mono_(__float_as_uint(p[e]));
        u64 kk = (((u64)(~mu)) << 24) | (u32)(s0 + e);
        if ((kk & himask) == (pref & himask)) atomicAdd(&h16[(int)((kk >> shift) & 15)], 1);
      }
      __syncthreads();
      if (tid == 0){
        int r2 = sh_rem, cum = 0;
        for (int d = 0; d < 16; d++){
          int hb = h16[d];
          if (cum + hb >= r2){ sh_thr = pref | ((u64)d << shift); sh_rem = r2 - cum; break; }
          cum += hb;
        }
      }
      __syncthreads();
    }
    u64 thr = sh_thr;
    for (int e = tid; e < n; e += 1024){
      u32 mu = mono_(__float_as_uint(p[e]));
      u64 kk = (((u64)(~mu)) << 24) | (u32)(s0 + e);
      if ((int)(kk >> 44) == bs && kk <= thr){ int p2 = atomicAdd(&sh_sc, 1); mainL[nb + p2] = kk; }
    }
  }
  __syncthreads();
  // --- bitonic sort 1024 ---
  for (int k2 = 2; k2 <= 1024; k2 <<= 1){
    for (int j = k2 >> 1; j > 0; j >>= 1){
      __syncthreads();
      int i = tid, ixj = i ^ j;
      if (ixj > i){
        u64 a = mainL[i], b = mainL[ixj];
        bool up = (i & k2) == 0;
        if ((a > b) == up){ mainL[i] = b; mainL[ixj] = a; }
      }
    }
  }
  __syncthreads();
  // --- decode + clip + valid + sigmoid + okey ---
  int r = tid, t = g*1024 + r;
  if (r < k){
    int idx = (int)(mainL[r] & 0xFFFFFFu);
    float4 a = anchors[idx];
    float4 d = deltas[img*R_TOT + idx];
    float o = obj[img*R_TOT + idx];
    float wa = fsub_(a.z, a.x), ha = fsub_(a.w, a.y);
    float cxa = fadd_(a.x, fmul_(0.5f, wa)), cya = fadd_(a.y, fmul_(0.5f, ha));
    float dw = fminf(d.z, BBOX_CLIP), dh = fminf(d.w, BBOX_CLIP);
    float cx = fadd_(fmul_(d.x, wa), cxa), cy = fadd_(fmul_(d.y, ha), cya);
    float w  = fmul_(expf(dw), wa),        h  = fmul_(expf(dh), ha);
    float x1 = fsub_(cx, fmul_(0.5f, w)), y1 = fsub_(cy, fmul_(0.5f, h));
    float x2 = fadd_(cx, fmul_(0.5f, w)), y2 = fadd_(cy, fmul_(0.5f, h));
    x1 = fminf(fmaxf(x1, 0.0f), IMG_SZ); y1 = fminf(fmaxf(y1, 0.0f), IMG_SZ);
    x2 = fminf(fmaxf(x2, 0.0f), IMG_SZ); y2 = fminf(fmaxf(y2, 0.0f), IMG_SZ);
    bool valid = (fsub_(x2, x1) >= 1e-3f) && (fsub_(y2, y1) >= 1e-3f);
    float e = expf(-o);
    float sig = __fdiv_rn(1.0f, fadd_(1.0f, e));
    float s = valid ? sig : -1.0f;
    u32 sb = __float_as_uint(s);
    u32 ms = (sb & 0x80000000u) ? ~sb : (sb | 0x80000000u);
    float4 b4 = make_float4(x1, y1, x2, y2);
    boxL[t] = b4;
    scoreL[t] = sig;
    lokey[r] = (((u64)(~ms)) << 32) | (u32)(lvl*1000 + r);
    lbox[r] = b4;
    lval[r] = valid ? 1 : 0;
  } else {
    lval[r] = 0;
  }
  __syncthreads();
  // --- valid-compaction (wave 0): nbox (+801*lvl offset) and okey in compacted order ---
  if (tid < 64){
    int cnt = 0;
    float off = (float)lvl * 801.0f;
    for (int base = 0; base < k; base += 64){
      int r2 = base + lane;
      bool v = (r2 < k) && lval[r2];
      float4 b = lbox[r2 < k ? r2 : 0];
      u64 mask = __ballot(v);
      int before = __popcll(mask & ((1ull << lane) - 1ull));
      if (v){
        int pos = cnt + before;
        nbox[g*1024 + pos] = make_float4(fadd_(b.x,off), fadd_(b.y,off), fadd_(b.z,off), fadd_(b.w,off));
        okeyN[g*1024 + pos] = lokey[r2];
      }
      cnt += __popcll(mask);
    }
    if (lane == 0) ncnt[g] = cnt;
  }
}

// ---------- 4. IoU bitmask: packed column-major triangle + forward diagonal words ----------
__global__ __launch_bounds__(64) void k_mask(const float4* __restrict__ nbox,
                                             const int* __restrict__ ncnt,
                                             u64* LTG, u64* diagF){
  int g = blockIdx.x, tr = blockIdx.y, tw = blockIdx.z;
  if (tw > tr) return;
  int m = ncnt[g];
  if (tr*64 >= m) return;
  __shared__ float4 shb[64];
  int lane = threadIdx.x;
  if (tw*64 + lane < m) shb[lane] = nbox[g*1024 + tw*64 + lane];
  __syncthreads();
  int j = tr*64 + lane;
  if (j >= m) return;
  float4 a = nbox[g*1024 + j];
  float areaA = fmul_(fsub_(a.z,a.x), fsub_(a.w,a.y));
  int imax = m - tw*64; if (imax > 64) imax = 64;
  if (tw == tr){
    // diagonal: only forward word (whom lane suppresses, ii > lane)
    u64 bitsF = 0;
    for (int ii = lane+1; ii < imax; ii++){
      float4 b = shb[ii];
      float ltx = fmaxf(a.x, b.x), lty = fmaxf(a.y, b.y);
      float rbx = fminf(a.z, b.z), rby = fminf(a.w, b.w);
      float wx = fmaxf(fsub_(rbx, ltx), 0.0f), wy = fmaxf(fsub_(rby, lty), 0.0f);
      float inter = fmul_(wx, wy);
      float areaB = fmul_(fsub_(b.z,b.x), fsub_(b.w,b.y));
      float den = fadd_(fsub_(fadd_(areaA, areaB), inter), 1e-9f);
      if (__fdiv_rn(inter, den) > NMS_TH) bitsF |= (1ull << ii);
    }
    diagF[g*1024 + j] = bitsF;
  } else {
    u64 bits = 0;
    for (int ii = 0; ii < imax; ii++){
      float4 b = shb[ii];
      float ltx = fmaxf(a.x, b.x), lty = fmaxf(a.y, b.y);
      float rbx = fminf(a.z, b.z), rby = fminf(a.w, b.w);
      float wx = fmaxf(fsub_(rbx, ltx), 0.0f), wy = fmaxf(fsub_(rby, lty), 0.0f);
      float inter = fmul_(wx, wy);
      float areaB = fmul_(fsub_(b.z,b.x), fsub_(b.w,b.y));
      float den = fadd_(fsub_(fadd_(areaA, areaB), inter), 1e-9f);
      if (__fdiv_rn(inter, den) > NMS_TH) bits |= (1ull << ii);
    }
    // packed column-major: word tw of row (tr*64+lane) at [tri(tr) + tw*64 + lane]
    LTG[(size_t)g*TRI_FULL + ((tr*(tr-1))/2 + tw)*64 + lane] = bits;
  }
}

__device__ __forceinline__ int lbound(const u64* a, int n, u64 key){
  int lo = 0, hi = n;
  while (lo < hi){ int mid = (lo + hi) >> 1; if (a[mid] < key) lo = mid + 1; else hi = mid; }
  return lo;
}

// ---------- 5. fused greedy scan + merge: waves 0-4 scan the 5 levels with BATCHED
//             triangle loads (15 unconditional clamped loads -> one waitcnt per chunk,
//             instead of one serialized far-memory latency per word); waves 5-15 zero
//             the output; then rank by binary search and scatter ----------
__global__ __launch_bounds__(1024) void k_scanmerge(const u64* __restrict__ LTG,
                                                    const u64* __restrict__ diagF,
                                                    const int* __restrict__ ncnt,
                                                    const u64* __restrict__ okeyN,
                                                    const float4* __restrict__ boxL,
                                                    const float* __restrict__ scoreL,
                                                    float* out){
  int img = blockIdx.x, tid = threadIdx.x, lane = tid & 63, wid = tid >> 6;
  __shared__ u64 runs[5*1024];
  __shared__ u64 Kw[5][16];
  __shared__ int cl[5];
  if (wid < 5){
    int l = wid, g = img*5 + l;
    int m = ncnt[g];
    int nch = (m + 63) >> 6;
    const u64* LT = LTG + (size_t)g*TRI_FULL;
    int cnt = 0;
    for (int c = 0; c < nch; c++){
      int row = c*64 + lane;              // row < 1024 always (c<=15)
      bool inr = row < m;
      int tb = (c*(c-1)) >> 1;
      // --- batched issue: 15 clamped unconditional triangle loads + diagF + okey ---
      u64 pre[15];
      #pragma unroll
      for (int q = 0; q < 15; q++){
        int qa = (q < c) ? q : 0;         // clamp -> address always valid, load unconditional
        pre[q] = LT[(tb + qa)*64 + lane];
      }
      u64 fwd_raw = diagF[g*1024 + row];
      u64 okey_raw = okeyN[g*1024 + row];
      #pragma unroll
      for (int q = 0; q < 15; q++){
        if (q >= c) pre[q] = 0;
      }
      u64 supp = 0;
      #pragma unroll
      for (int q = 0; q < 15; q++) supp |= pre[q] & Kw[l][q];
      u64 fwd = inr ? fwd_raw : 0;
      u64 live = __ballot(inr && (supp == 0));
      u64 fz = __ballot(fwd != 0);
      u64 kept = 0;
      while (live){
        if (!(live & fz)){ kept |= live; break; }   // no remaining live lane suppresses anyone
        int i = __builtin_ctzll(live);
        kept |= (1ull << i);
        live &= ~(1ull << i);
        live &= ~readlane64(fwd, i);
      }
      Kw[l][c] = kept;                // uniform value; in-wave DS ordering suffices
      bool kp = (kept >> lane) & 1ull;
      int before = __popcll(kept & ((1ull << lane) - 1ull));
      if (kp) runs[l*1024 + cnt + before] = okey_raw;
      cnt += __popcll(kept);
    }
    if (lane == 0) cl[l] = cnt;
  } else {
    // 704 threads zero the output while the scans run
    for (int t = tid - 320; t < POST; t += 704){
      out[img*POST*4 + t*4 + 0] = 0.0f;
      out[img*POST*4 + t*4 + 1] = 0.0f;
      out[img*POST*4 + t*4 + 2] = 0.0f;
      out[img*POST*4 + t*4 + 3] = 0.0f;
      out[2*POST*4 + img*POST + t] = -1.0f;
    }
  }
  __syncthreads();
  for (int idx = tid; idx < 5*1024; idx += 1024){
    int l = idx >> 10, i = idx & 1023;
    if (i < cl[l]){
      u64 key = runs[l*1024 + i];
      int rank = i;
      #pragma unroll
      for (int l2 = 0; l2 < 5; l2++)
        if (l2 != l) rank += lbound(runs + l2*1024, cl[l2], key);
      if (rank < POST){
        int pos = (int)(key & 0xFFFFFFFFull);
        int lvl = pos / 1000, r = pos - lvl*1000;
        int gg = img*5 + lvl;
        float4 bo = boxL[gg*1024 + r];
        float sc = scoreL[gg*1024 + r];
        out[img*POST*4 + rank*4 + 0] = bo.x;
        out[img*POST*4 + rank*4 + 1] = bo.y;
        out[img*POST*4 + rank*4 + 2] = bo.z;
        out[img*POST*4 + rank*4 + 3] = bo.w;
        out[2*POST*4 + img*POST + rank] = sc;
      }
    }
  }
}

extern "C" void kernel_launch(void* const* d_in, const int* in_sizes, int n_in,
                              void* d_out, int out_size, void* d_ws, size_t ws_size,
                              hipStream_t stream){
  (void)in_sizes; (void)n_in; (void)out_size; (void)ws_size;
  const float*  obj     = (const float*)d_in[0];
  const float4* deltas  = (const float4*)d_in[1];
  const float4* anchors = (const float4*)d_in[2];
  float* out = (float*)d_out;
  char* ws = (char*)d_ws;
  int* hist16  = (int*)(ws + 0);           // 10*16*4096 int -> 2621440
  int* bstarG  = (int*)(ws + 2621440);     //                -> 2621696
  int* remG    = (int*)(ws + 2621696);     //                -> 2621952
  int* cntg    = (int*)(ws + 2621952);     //                -> 2622208
  int* cnt2    = (int*)(ws + 2622208);     //                -> 2622464
  u64* mainG   = (u64*)(ws + 2622464);     // 10*1024 u64    -> 2704384
  u64* LbufG   = (u64*)(ws + 2704384);     // 10*1024 u64    -> 2786304
  float4* boxL = (float4*)(ws + 2786304);  // 10*1024 f4     -> 2950144
  float* scoreL= (float*)(ws + 2950144);   // 10*1024 f32    -> 2991104
  u64* okeyN   = (u64*)(ws + 2991104);     // 10*1024 u64    -> 3073024
  float4* nbox = (float4*)(ws + 3073024);  // 10*1024 f4     -> 3236864
  u64* LTG     = (u64*)(ws + 3236864);     // 10*7680 u64    -> 3851264
  u64* diagF   = (u64*)(ws + 3851264);     // 10*1024 u64    -> 3933184
  int* ncnt    = (int*)(ws + 3934464);     // 10 int

  {
    dim3 gh(10, 16);
    k_hist<<<gh, 256, 0, stream>>>(obj, hist16, cntg, cnt2);
  }
  {
    dim3 gc(10, 16);
    k_collect<<<gc, 256, 0, stream>>>(obj, hist16, bstarG, remG, cntg, cnt2, mainG, LbufG);
  }
  k_seldecode<<<10, 1024, 0, stream>>>(obj, deltas, anchors, mainG, LbufG, cntg, cnt2,
                                       remG, bstarG, boxL, scoreL, nbox, okeyN, ncnt);
  {
    dim3 gm(10, 16, 16);
    k_mask<<<gm, 64, 0, stream>>>(nbox, ncnt, LTG, diagF);
  }
  k_scanmerge<<<2, 1024, 0, stream>>>(LTG, diagF, ncnt, okeyN, boxL, scoreL, out);
}

// Round 3
// 157.584 us; speedup vs baseline: 1.3200x; 1.1119x over previous
//
#include <hip/hip_runtime.h>

typedef unsigned long long u64;
typedef unsigned int u32;

#define R_TOT 159882
#define POST 1000
#define IMG_SZ 800.0f
#define NMS_TH 0.7f
#define BBOX_CLIP 4.135166556742356f
#define LCAP 1024

__device__ __forceinline__ float fadd_(float a, float b){ return __fadd_rn(a,b); }
__device__ __forceinline__ float fsub_(float a, float b){ return __fsub_rn(a,b); }
__device__ __forceinline__ float fmul_(float a, float b){ return __fmul_rn(a,b); }

__device__ __forceinline__ int lvl_len(int l){ const int L[5]={120000,30000,7500,1875,507}; return L[l]; }
__device__ __forceinline__ int lvl_off(int l){ const int L[5]={0,120000,150000,157500,159375}; return L[l]; }
__device__ __forceinline__ int lvl_k(int l){ const int L[5]={1000,1000,1000,1000,507}; return L[l]; }

__device__ __forceinline__ u32 mono_(u32 u){ return (u & 0x80000000u) ? ~u : (u | 0x80000000u); }

__device__ __forceinline__ u64 readlane64(u64 v, int i){
  u32 lo = (u32)__builtin_amdgcn_readlane((int)(u32)v, i);
  u32 hi = (u32)__builtin_amdgcn_readlane((int)(u32)(v >> 32), i);
  return ((u64)hi << 32) | (u64)lo;
}

// ---------- 1. per-slice 12-bit histogram ----------
__global__ __launch_bounds__(256) void k_hist(const float* __restrict__ obj, int* hist16,
                                              int* cntg, int* cnt2){
  int g = blockIdx.x, sl = blockIdx.y;
  int img = g/5, lvl = g%5;
  int n = lvl_len(lvl), s0 = lvl_off(lvl);
  __shared__ int lh[4096];
  int tid = threadIdx.x;
  for (int i = tid; i < 4096; i += 256) lh[i] = 0;
  if (sl == 0 && tid == 0){ cntg[g] = 0; cnt2[g] = 0; }
  __syncthreads();
  int lo = (int)((long long)n * sl / 16), hiS = (int)((long long)n * (sl+1) / 16);
  const float* p = obj + img*R_TOT + s0;
  #pragma unroll 4
  for (int e = lo + tid; e < hiS; e += 256){
    u32 mu = mono_(__float_as_uint(p[e]));
    atomicAdd(&lh[(~mu) >> 20], 1);
  }
  __syncthreads();
  int* dst = hist16 + (g*16 + sl)*4096;
  for (int i = tid; i < 4096; i += 256) dst[i] = lh[i];
}

// ---------- 2. collect with inlined pick ----------
__global__ __launch_bounds__(256) void k_collect(const float* __restrict__ obj,
                                                 const int* __restrict__ hist16,
                                                 int* bstarG, int* remG,
                                                 int* cntg, int* cnt2,
                                                 u64* mainG, u64* LbufG){
  int g = blockIdx.x, sl = blockIdx.y;
  int img = g/5, lvl = g%5;
  int n = lvl_len(lvl), s0 = lvl_off(lvl), k = lvl_k(lvl);
  int tid = threadIdx.x, lane = tid & 63, wid = tid >> 6;
  __shared__ int wsum[4];
  __shared__ int sh_bs, sh_rem;
  __shared__ int lc, lc2, gbase, gbase2;
  __shared__ u64 lmain[1024];
  __shared__ u64 lbuf2[1024];

  int h[16];
  #pragma unroll
  for (int j = 0; j < 16; j++) h[j] = 0;
  const int* hb = hist16 + g*16*4096 + 16*tid;
  for (int s2 = 0; s2 < 16; s2++){
    const int4* hs = (const int4*)(hb + s2*4096);
    int4 a = hs[0], b = hs[1], c = hs[2], d = hs[3];
    h[0]+=a.x;  h[1]+=a.y;  h[2]+=a.z;  h[3]+=a.w;
    h[4]+=b.x;  h[5]+=b.y;  h[6]+=b.z;  h[7]+=b.w;
    h[8]+=c.x;  h[9]+=c.y;  h[10]+=c.z; h[11]+=c.w;
    h[12]+=d.x; h[13]+=d.y; h[14]+=d.z; h[15]+=d.w;
  }
  int part = 0;
  #pragma unroll
  for (int j = 0; j < 16; j++) part += h[j];
  int x = part;
  for (int d = 1; d < 64; d <<= 1){ int y = __shfl_up(x, d); if (lane >= d) x += y; }
  if (lane == 63) wsum[wid] = x;
  if (tid == 0){ lc = 0; lc2 = 0; }
  __syncthreads();
  int add = 0;
  for (int w = 0; w < wid; w++) add += wsum[w];
  int incl = x + add, excl = incl - part;
  if (excl < k && k <= incl){
    int cum = excl;
    #pragma unroll
    for (int q = 0; q < 16; q++){
      if (cum + h[q] >= k){ sh_bs = 16*tid + q; sh_rem = k - cum; break; }
      cum += h[q];
    }
  }
  __syncthreads();
  int bs = sh_bs;
  if (sl == 0 && tid == 0){ bstarG[g] = bs; remG[g] = sh_rem; }

  int lo = (int)((long long)n * sl / 16), hiS = (int)((long long)n * (sl+1) / 16);
  const float* p = obj + img*R_TOT + s0;
  #pragma unroll 4
  for (int e = lo + tid; e < hiS; e += 256){
    u32 mu = mono_(__float_as_uint(p[e]));
    u64 key56 = (((u64)(~mu)) << 24) | (u32)(s0 + e);
    int bin = (int)(key56 >> 44);
    if (bin < bs){ int pos = atomicAdd(&lc, 1); lmain[pos] = key56; }
    else if (bin == bs){ int pos = atomicAdd(&lc2, 1); if (pos < 1024) lbuf2[pos] = key56; }
  }
  __syncthreads();
  if (tid == 0){ gbase = atomicAdd(&cntg[g], lc); gbase2 = atomicAdd(&cnt2[g], lc2); }
  __syncthreads();
  int b1 = gbase, c1 = lc;
  for (int i = tid; i < c1; i += 256) mainG[g*1024 + b1 + i] = lmain[i];
  int b2 = gbase2, c2l = lc2 < 1024 ? lc2 : 1024;
  for (int i = tid; i < c2l; i += 256){
    int gp = b2 + i;
    if (gp < LCAP) LbufG[g*LCAP + gp] = lbuf2[i];
  }
}

// ---------- 3. tie-resolve + sort + decode + prep ----------
__global__ __launch_bounds__(1024) void k_seldecode(const float* __restrict__ obj,
                                                    const float4* __restrict__ deltas,
                                                    const float4* __restrict__ anchors,
                                                    const u64* __restrict__ mainG,
                                                    const u64* __restrict__ LbufG,
                                                    const int* __restrict__ cntg,
                                                    const int* __restrict__ cnt2,
                                                    const int* __restrict__ remG,
                                                    const int* __restrict__ bstarG,
                                                    float4* boxL, float* scoreL,
                                                    float4* nbox, u64* okeyN, int* ncnt){
  int g = blockIdx.x, img = g/5, lvl = g%5;
  int s0 = lvl_off(lvl), n = lvl_len(lvl), k = lvl_k(lvl);
  const float* p = obj + img*R_TOT + s0;
  __shared__ u64 Lbuf[LCAP];
  __shared__ u64 mainL[1024];
  __shared__ float4 lbox[1024];
  __shared__ u64 lokey[1024];
  __shared__ unsigned char lval[1024];
  __shared__ int h16[16];
  __shared__ int sh_sc, sh_rem;
  __shared__ u64 sh_thr;
  int tid = threadIdx.x, lane = tid & 63;
  int nb = cntg[g];
  int c2 = cnt2[g];
  int rem = remG[g];
  int bs = bstarG[g];
  mainL[tid] = (tid < nb) ? mainG[g*1024 + tid] : ~0ull;
  if (tid == 0){ sh_sc = 0; sh_rem = rem; }
  int c2c = c2 < LCAP ? c2 : LCAP;
  for (int e = tid; e < c2c; e += 1024) Lbuf[e] = LbufG[g*LCAP + e];
  __syncthreads();
  if (c2 <= LCAP){
    for (int e = tid; e < c2; e += 1024){
      u64 kk = Lbuf[e];
      int rk = 0;
      for (int q = 0; q < c2; q++) rk += (Lbuf[q] < kk) ? 1 : 0;
      if (rk < rem){ int p2 = atomicAdd(&sh_sc, 1); mainL[nb + p2] = kk; }
    }
  } else {
    if (tid == 0) sh_thr = ((u64)bs) << 44;
    __syncthreads();
    for (int shift = 40; shift >= 0; shift -= 4){
      if (tid < 16) h16[tid] = 0;
      __syncthreads();
      u64 pref = sh_thr;
      u64 himask = ~((1ull << (shift+4)) - 1ull);
      for (int e = tid; e < n; e += 1024){
        u32 mu = mono_(__float_as_uint(p[e]));
        u64 kk = (((u64)(~mu)) << 24) | (u32)(s0 + e);
        if ((kk & himask) == (pref & himask)) atomicAdd(&h16[(int)((kk >> shift) & 15)], 1);
      }
      __syncthreads();
      if (tid == 0){
        int r2 = sh_rem, cum = 0;
        for (int d = 0; d < 16; d++){
          int hb = h16[d];
          if (cum + hb >= r2){ sh_thr = pref | ((u64)d << shift); sh_rem = r2 - cum; break; }
          cum += hb;
        }
      }
      __syncthreads();
    }
    u64 thr = sh_thr;
    for (int e = tid; e < n; e += 1024){
      u32 mu = mono_(__float_as_uint(p[e]));
      u64 kk = (((u64)(~mu)) << 24) | (u32)(s0 + e);
      if ((int)(kk >> 44) == bs && kk <= thr){ int p2 = atomicAdd(&sh_sc, 1); mainL[nb + p2] = kk; }
    }
  }
  __syncthreads();
  for (int k2 = 2; k2 <= 1024; k2 <<= 1){
    for (int j = k2 >> 1; j > 0; j >>= 1){
      __syncthreads();
      int i = tid, ixj = i ^ j;
      if (ixj > i){
        u64 a = mainL[i], b = mainL[ixj];
        bool up = (i & k2) == 0;
        if ((a > b) == up){ mainL[i] = b; mainL[ixj] = a; }
      }
    }
  }
  __syncthreads();
  int r = tid, t = g*1024 + r;
  if (r < k){
    int idx = (int)(mainL[r] & 0xFFFFFFu);
    float4 a = anchors[idx];
    float4 d = deltas[img*R_TOT + idx];
    float o = obj[img*R_TOT + idx];
    float wa = fsub_(a.z, a.x), ha = fsub_(a.w, a.y);
    float cxa = fadd_(a.x, fmul_(0.5f, wa)), cya = fadd_(a.y, fmul_(0.5f, ha));
    float dw = fminf(d.z, BBOX_CLIP), dh = fminf(d.w, BBOX_CLIP);
    float cx = fadd_(fmul_(d.x, wa), cxa), cy = fadd_(fmul_(d.y, ha), cya);
    float w  = fmul_(expf(dw), wa),        h  = fmul_(expf(dh), ha);
    float x1 = fsub_(cx, fmul_(0.5f, w)), y1 = fsub_(cy, fmul_(0.5f, h));
    float x2 = fadd_(cx, fmul_(0.5f, w)), y2 = fadd_(cy, fmul_(0.5f, h));
    x1 = fminf(fmaxf(x1, 0.0f), IMG_SZ); y1 = fminf(fmaxf(y1, 0.0f), IMG_SZ);
    x2 = fminf(fmaxf(x2, 0.0f), IMG_SZ); y2 = fminf(fmaxf(y2, 0.0f), IMG_SZ);
    bool valid = (fsub_(x2, x1) >= 1e-3f) && (fsub_(y2, y1) >= 1e-3f);
    float e = expf(-o);
    float sig = __fdiv_rn(1.0f, fadd_(1.0f, e));
    float s = valid ? sig : -1.0f;
    u32 sb = __float_as_uint(s);
    u32 ms = (sb & 0x80000000u) ? ~sb : (sb | 0x80000000u);
    float4 b4 = make_float4(x1, y1, x2, y2);
    boxL[t] = b4;
    scoreL[t] = sig;
    lokey[r] = (((u64)(~ms)) << 32) | (u32)(lvl*1000 + r);
    lbox[r] = b4;
    lval[r] = valid ? 1 : 0;
  } else {
    lval[r] = 0;
  }
  __syncthreads();
  if (tid < 64){
    int cnt = 0;
    float off = (float)lvl * 801.0f;
    for (int base = 0; base < k; base += 64){
      int r2 = base + lane;
      bool v = (r2 < k) && lval[r2];
      float4 b = lbox[r2 < k ? r2 : 0];
      u64 mask = __ballot(v);
      int before = __popcll(mask & ((1ull << lane) - 1ull));
      if (v){
        int pos = cnt + before;
        nbox[g*1024 + pos] = make_float4(fadd_(b.x,off), fadd_(b.y,off), fadd_(b.z,off), fadd_(b.w,off));
        okeyN[g*1024 + pos] = lokey[r2];
      }
      cnt += __popcll(mask);
    }
    if (lane == 0) ncnt[g] = cnt;
  }
}

// ---------- 4. IoU bitmask: ROW-MAJOR layout LTG2[row*16 + q], diagF in slot 15 ----------
__global__ __launch_bounds__(64) void k_mask(const float4* __restrict__ nbox,
                                             const int* __restrict__ ncnt,
                                             u64* LTG2){
  int g = blockIdx.x, tr = blockIdx.y, tw = blockIdx.z;
  if (tw > tr) return;
  int m = ncnt[g];
  if (tr*64 >= m) return;
  __shared__ float4 shb[64];
  int lane = threadIdx.x;
  if (tw*64 + lane < m) shb[lane] = nbox[g*1024 + tw*64 + lane];
  __syncthreads();
  int j = tr*64 + lane;
  if (j >= m) return;
  float4 a = nbox[g*1024 + j];
  float areaA = fmul_(fsub_(a.z,a.x), fsub_(a.w,a.y));
  int imax = m - tw*64; if (imax > 64) imax = 64;
  if (tw == tr){
    u64 bitsF = 0;
    for (int ii = lane+1; ii < imax; ii++){
      float4 b = shb[ii];
      float ltx = fmaxf(a.x, b.x), lty = fmaxf(a.y, b.y);
      float rbx = fminf(a.z, b.z), rby = fminf(a.w, b.w);
      float wx = fmaxf(fsub_(rbx, ltx), 0.0f), wy = fmaxf(fsub_(rby, lty), 0.0f);
      float inter = fmul_(wx, wy);
      float areaB = fmul_(fsub_(b.z,b.x), fsub_(b.w,b.y));
      float den = fadd_(fsub_(fadd_(areaA, areaB), inter), 1e-9f);
      if (__fdiv_rn(inter, den) > NMS_TH) bitsF |= (1ull << ii);
    }
    LTG2[((size_t)(g*1024 + j))*16 + 15] = bitsF;
  } else {
    u64 bits = 0;
    for (int ii = 0; ii < imax; ii++){
      float4 b = shb[ii];
      float ltx = fmaxf(a.x, b.x), lty = fmaxf(a.y, b.y);
      float rbx = fminf(a.z, b.z), rby = fminf(a.w, b.w);
      float wx = fmaxf(fsub_(rbx, ltx), 0.0f), wy = fmaxf(fsub_(rby, lty), 0.0f);
      float inter = fmul_(wx, wy);
      float areaB = fmul_(fsub_(b.z,b.x), fsub_(b.w,b.y));
      float den = fadd_(fsub_(fadd_(areaA, areaB), inter), 1e-9f);
      if (__fdiv_rn(inter, den) > NMS_TH) bits |= (1ull << ii);
    }
    LTG2[((size_t)(g*1024 + j))*16 + tw] = bits;
  }
}

__device__ __forceinline__ int lbound(const u64* a, int n, u64 key){
  int lo = 0, hi = n;
  while (lo < hi){ int mid = (lo + hi) >> 1; if (a[mid] < key) lo = mid + 1; else hi = mid; }
  return lo;
}

struct ChunkBuf {
  ulonglong2 v0, v1, v2, v3, v4, v5, v6, v7;   // 16 u64: words 0..14 + diagF (slot 15)
  u64 ok;
};

__device__ __forceinline__ void issue_chunk(const u64* __restrict__ LT2,
                                            const u64* __restrict__ oK,
                                            int c, int lane, ChunkBuf& b){
  int row = c*64 + lane;
  const ulonglong2* rp = (const ulonglong2*)(LT2 + (size_t)row*16);
  b.v0 = rp[0]; b.v1 = rp[1]; b.v2 = rp[2]; b.v3 = rp[3];
  b.v4 = rp[4]; b.v5 = rp[5]; b.v6 = rp[6]; b.v7 = rp[7];
  b.ok = oK[row];
}

__device__ __forceinline__ void consume_chunk(const ChunkBuf& b, int c, int m, int lane,
                                              u64* KwR, u64* runsL, int& cnt){
  int row = c*64 + lane;
  bool inr = row < m;
  u64 supp = 0;
  #define TERM(q, val) supp |= (((q) < c) ? (val) : 0ull) & KwR[q];
  TERM(0,  b.v0.x) TERM(1,  b.v0.y) TERM(2,  b.v1.x) TERM(3,  b.v1.y)
  TERM(4,  b.v2.x) TERM(5,  b.v2.y) TERM(6,  b.v3.x) TERM(7,  b.v3.y)
  TERM(8,  b.v4.x) TERM(9,  b.v4.y) TERM(10, b.v5.x) TERM(11, b.v5.y)
  TERM(12, b.v6.x) TERM(13, b.v6.y) TERM(14, b.v7.x)
  #undef TERM
  u64 fwd = inr ? b.v7.y : 0;
  u64 live = __ballot(inr && (supp == 0));
  u64 fz = __ballot(fwd != 0);
  u64 kept = 0;
  while (1){
    u64 lf = live & fz;
    if (!lf){ kept |= live; break; }       // remaining live lanes suppress nobody
    int i = __builtin_ctzll(lf);
    u64 bi = 1ull << i;
    u64 below = live & (bi - 1ull);        // live lanes before i: fwd==0, batch-keep
    kept |= below | bi;
    live &= ~(below | bi);
    live &= ~readlane64(fwd, i);
  }
  KwR[c] = kept;                            // uniform; in-wave DS ordering suffices
  bool kp = (kept >> lane) & 1ull;
  int before = __popcll(kept & ((1ull << lane) - 1ull));
  if (kp) runsL[cnt + before] = b.ok;
  cnt += __popcll(kept);
}

// ---------- 5. fused greedy scan + merge: double-buffered chunk pipeline + skip-pop;
//             rank via 4-way interleaved binary search ----------
__global__ __launch_bounds__(1024) void k_scanmerge(const u64* __restrict__ LTG2,
                                                    const int* __restrict__ ncnt,
                                                    const u64* __restrict__ okeyN,
                                                    const float4* __restrict__ boxL,
                                                    const float* __restrict__ scoreL,
                                                    float* out){
  int img = blockIdx.x, tid = threadIdx.x, lane = tid & 63, wid = tid >> 6;
  __shared__ u64 runs[5*1024];
  __shared__ u64 Kw[5][16];
  __shared__ int cl[5];
  if (wid < 5){
    int l = wid, g = img*5 + l;
    int m = ncnt[g];
    int nch = (m + 63) >> 6;
    const u64* LT2 = LTG2 + ((size_t)g*1024)*16;
    const u64* oK = okeyN + g*1024;
    u64* KwR = &Kw[l][0];
    u64* runsL = &runs[l*1024];
    int cnt = 0;
    ChunkBuf A, B;
    if (nch > 0){
      issue_chunk(LT2, oK, 0, lane, A);
      int c = 0;
      while (c < nch){
        if (c+1 < nch) issue_chunk(LT2, oK, c+1, lane, B);
        consume_chunk(A, c, m, lane, KwR, runsL, cnt);
        c++;
        if (c >= nch) break;
        if (c+1 < nch) issue_chunk(LT2, oK, c+1, lane, A);
        consume_chunk(B, c, m, lane, KwR, runsL, cnt);
        c++;
      }
    }
    if (lane == 0) cl[l] = cnt;
  } else {
    for (int t = tid - 320; t < POST; t += 704){
      out[img*POST*4 + t*4 + 0] = 0.0f;
      out[img*POST*4 + t*4 + 1] = 0.0f;
      out[img*POST*4 + t*4 + 2] = 0.0f;
      out[img*POST*4 + t*4 + 3] = 0.0f;
      out[2*POST*4 + img*POST + t] = -1.0f;
    }
  }
  __syncthreads();
  for (int idx = tid; idx < 5*1024; idx += 1024){
    int l = idx >> 10, i = idx & 1023;
    if (i < cl[l]){
      u64 key = runs[l*1024 + i];
      int o0 = l+1; if (o0 >= 5) o0 -= 5;
      int o1 = l+2; if (o1 >= 5) o1 -= 5;
      int o2 = l+3; if (o2 >= 5) o2 -= 5;
      int o3 = l+4; if (o3 >= 5) o3 -= 5;
      const u64* r0 = runs + (o0 << 10);
      const u64* r1 = runs + (o1 << 10);
      const u64* r2 = runs + (o2 << 10);
      const u64* r3 = runs + (o3 << 10);
      int lo0 = 0, hi0 = cl[o0];
      int lo1 = 0, hi1 = cl[o1];
      int lo2 = 0, hi2 = cl[o2];
      int lo3 = 0, hi3 = cl[o3];
      #pragma unroll 1
      for (int st = 0; st < 11; st++){
        int m0 = (lo0+hi0)>>1, m1 = (lo1+hi1)>>1, m2 = (lo2+hi2)>>1, m3 = (lo3+hi3)>>1;
        u64 a0 = r0[m0], a1 = r1[m1], a2 = r2[m2], a3 = r3[m3];
        if (lo0 < hi0){ if (a0 < key) lo0 = m0+1; else hi0 = m0; }
        if (lo1 < hi1){ if (a1 < key) lo1 = m1+1; else hi1 = m1; }
        if (lo2 < hi2){ if (a2 < key) lo2 = m2+1; else hi2 = m2; }
        if (lo3 < hi3){ if (a3 < key) lo3 = m3+1; else hi3 = m3; }
      }
      int rank = i + lo0 + lo1 + lo2 + lo3;
      if (rank < POST){
        int pos = (int)(key & 0xFFFFFFFFull);
        int lvl = pos / 1000, r = pos - lvl*1000;
        int gg = img*5 + lvl;
        float4 bo = boxL[gg*1024 + r];
        float sc = scoreL[gg*1024 + r];
        out[img*POST*4 + rank*4 + 0] = bo.x;
        out[img*POST*4 + rank*4 + 1] = bo.y;
        out[img*POST*4 + rank*4 + 2] = bo.z;
        out[img*POST*4 + rank*4 + 3] = bo.w;
        out[2*POST*4 + img*POST + rank] = sc;
      }
    }
  }
}

extern "C" void kernel_launch(void* const* d_in, const int* in_sizes, int n_in,
                              void* d_out, int out_size, void* d_ws, size_t ws_size,
                              hipStream_t stream){
  (void)in_sizes; (void)n_in; (void)out_size; (void)ws_size;
  const float*  obj     = (const float*)d_in[0];
  const float4* deltas  = (const float4*)d_in[1];
  const float4* anchors = (const float4*)d_in[2];
  float* out = (float*)d_out;
  char* ws = (char*)d_ws;
  int* hist16  = (int*)(ws + 0);           // 10*16*4096 int -> 2621440
  int* bstarG  = (int*)(ws + 2621440);     //                -> 2621696
  int* remG    = (int*)(ws + 2621696);     //                -> 2621952
  int* cntg    = (int*)(ws + 2621952);     //                -> 2622208
  int* cnt2    = (int*)(ws + 2622208);     //                -> 2622464
  u64* mainG   = (u64*)(ws + 2622464);     // 10*1024 u64    -> 2704384
  u64* LbufG   = (u64*)(ws + 2704384);     // 10*1024 u64    -> 2786304
  float4* boxL = (float4*)(ws + 2786304);  // 10*1024 f4     -> 2950144
  float* scoreL= (float*)(ws + 2950144);   // 10*1024 f32    -> 2991104
  u64* okeyN   = (u64*)(ws + 2991104);     // 10*1024 u64    -> 3073024
  float4* nbox = (float4*)(ws + 3073024);  // 10*1024 f4     -> 3236864
  u64* LTG2    = (u64*)(ws + 3236864);     // 10*1024*16 u64 -> 4547584
  int* ncnt    = (int*)(ws + 4547584);     // 10 int

  {
    dim3 gh(10, 16);
    k_hist<<<gh, 256, 0, stream>>>(obj, hist16, cntg, cnt2);
  }
  {
    dim3 gc(10, 16);
    k_collect<<<gc, 256, 0, stream>>>(obj, hist16, bstarG, remG, cntg, cnt2, mainG, LbufG);
  }
  k_seldecode<<<10, 1024, 0, stream>>>(obj, deltas, anchors, mainG, LbufG, cntg, cnt2,
                                       remG, bstarG, boxL, scoreL, nbox, okeyN, ncnt);
  {
    dim3 gm(10, 16, 16);
    k_mask<<<gm, 64, 0, stream>>>(nbox, ncnt, LTG2);
  }
  k_scanmerge<<<2, 1024, 0, stream>>>(LTG2, ncnt, okeyN, boxL, scoreL, out);
}